// Round 4
// baseline (1170.491 us; speedup 1.0000x reference)
//
#include <hip/hip_runtime.h>
#include <hip/hip_bf16.h>

#define USER_NUM 60000
#define ITEM_NUM 40000
#define NODE_NUM 100000
#define DIM 64
#define NNZ_N 1600000
#define BATCH 4096
#define NEG 0.2f
#define NCHUNK (NODE_NUM / 4)   // 25000 chunks of 4 rows

// ---------------- CSR build ----------------
__global__ void k_count(const int* __restrict__ row, int* __restrict__ deg, int n) {
    int i = blockIdx.x * 256 + threadIdx.x;
    if (i < n) atomicAdd(&deg[row[i]], 1);
}

// phase 1: per-block inclusive scan (1024 elems/block), write exclusive
__global__ void k_scan_blk(const int* __restrict__ deg, int* __restrict__ ptr,
                           int* __restrict__ bsums, int n) {
    __shared__ int sh[1024];
    int t = threadIdx.x;
    int i = blockIdx.x * 1024 + t;
    int v = (i < n) ? deg[i] : 0;
    sh[t] = v;
    __syncthreads();
    for (int d = 1; d < 1024; d <<= 1) {
        int x = (t >= d) ? sh[t - d] : 0;
        __syncthreads();
        sh[t] += x;
        __syncthreads();
    }
    if (i < n) ptr[i] = sh[t] - v;
    if (t == 1023) bsums[blockIdx.x] = sh[1023];
}

__global__ void k_scan_tops(int* bsums, int nb) {
    __shared__ int sh[128];
    int t = threadIdx.x;
    int v = (t < nb) ? bsums[t] : 0;
    sh[t] = v;
    __syncthreads();
    for (int d = 1; d < 128; d <<= 1) {
        int x = (t >= d) ? sh[t - d] : 0;
        __syncthreads();
        sh[t] += x;
        __syncthreads();
    }
    if (t < nb) bsums[t] = sh[t] - v;
}

__global__ void k_scan_add(int* __restrict__ ptr, const int* __restrict__ bsums, int n) {
    int i = blockIdx.x * 1024 + threadIdx.x;
    if (i < n) ptr[i] += bsums[blockIdx.x];
}

__global__ void k_copy_i32(const int* __restrict__ src, int* __restrict__ dst, int n) {
    int i = blockIdx.x * 1024 + threadIdx.x;
    if (i < n) dst[i] = src[i];
}

// scatter edges into CSR slots; cursor bumped, ptr keeps row starts
__global__ void k_scatter(const int* __restrict__ row, const int* __restrict__ col,
                          const float* __restrict__ vals, int* __restrict__ cursor,
                          int* __restrict__ ccol, float* __restrict__ cval, int n) {
    int i = blockIdx.x * 256 + threadIdx.x;
    if (i < n) {
        int r = row[i];
        int pos = atomicAdd(&cursor[r], 1);
        ccol[pos] = col[i];
        cval[pos] = vals[i];
    }
}

// ---------------- fused layer: SpMM + bi-interaction + 2 GEMMs + leaky-relu ----
// one wave per row (lane = dim); W1/W2 staged in LDS; grid-stride over chunks
__launch_bounds__(256)
__global__ void k_layer(const int* __restrict__ ptrS, const int* __restrict__ deg,
                        const int* __restrict__ ccol, const float* __restrict__ cval,
                        const float* __restrict__ Ein, const float* __restrict__ W1l,
                        const float* __restrict__ W2l, float* __restrict__ Eout) {
    __shared__ float w1[4096], w2[4096], su[256], bi[256];
    int t = threadIdx.x;
    for (int i = t; i < 4096; i += 256) { w1[i] = W1l[i]; w2[i] = W2l[i]; }
    __syncthreads();
    int rowl = t >> 6, d = t & 63;
    for (int ch = blockIdx.x; ch < NCHUNK; ch += gridDim.x) {
        int r = ch * 4 + rowl;
        int s0 = ptrS[r];
        int e0 = s0 + deg[r];
        float e = Ein[(size_t)r * 64 + d];
        float acc = 0.f;
        for (int i = s0; i < e0; ++i) {
            acc = fmaf(cval[i], Ein[(size_t)ccol[i] * 64 + d], acc);
        }
        su[t] = e + acc;   // t == rowl*64 + d
        bi[t] = e * acc;
        __syncthreads();
        float a1 = 0.f, a2 = 0.f;
#pragma unroll
        for (int k = 0; k < 64; k++) {
            a1 = fmaf(su[rowl * 64 + k], w1[k * 64 + d], a1);
            a2 = fmaf(bi[rowl * 64 + k], w2[k * 64 + d], a2);
        }
        float x = a1 + a2;
        Eout[(size_t)r * 64 + d] = x > 0.f ? x : NEG * x;
        __syncthreads();
    }
}

// ---------------- gather one 64-col layer block into fp32 output ----------------
__global__ void k_gather(const float* __restrict__ E, float* __restrict__ out,
                         const int* __restrict__ uidx, const int* __restrict__ iidx,
                         int layer) {
    int g = blockIdx.x * 256 + threadIdx.x;
    int b = g >> 6, d = g & 63;
    if (b >= 2 * BATCH) return;
    int node;
    size_t obase;
    if (b < BATCH) {
        node = uidx[b];
        obase = (size_t)b * 256;
    } else {
        int bb = b - BATCH;
        node = USER_NUM + iidx[bb];
        obase = (size_t)BATCH * 256 + (size_t)bb * 256;
    }
    out[obase + layer * 64 + d] = E[(size_t)node * 64 + d];
}

extern "C" void kernel_launch(void* const* d_in, const int* in_sizes, int n_in,
                              void* d_out, int out_size, void* d_ws, size_t ws_size,
                              hipStream_t stream) {
    const float* emb  = (const float*)d_in[0];
    const float* W1   = (const float*)d_in[1];
    const float* W2   = (const float*)d_in[2];
    const float* vals = (const float*)d_in[3];
    const int*   row  = (const int*)d_in[4];
    const int*   col  = (const int*)d_in[5];
    const int*   uidx = (const int*)d_in[6];
    const int*   iidx = (const int*)d_in[7];
    float* out = (float*)d_out;

    char* p = (char*)d_ws;
    auto alloc = [&](size_t bytes) -> void* {
        void* q = (void*)p;
        p += (bytes + 255) & ~(size_t)255;
        return q;
    };
    int*   deg    = (int*)alloc((size_t)NODE_NUM * 4);
    int*   ptr    = (int*)alloc((size_t)NODE_NUM * 4);
    int*   cursor = (int*)alloc((size_t)NODE_NUM * 4);
    int*   bsums  = (int*)alloc(128 * 4);
    int*   ccol   = (int*)alloc((size_t)NNZ_N * 4);
    float* cval   = (float*)alloc((size_t)NNZ_N * 4);
    float* F0     = (float*)alloc((size_t)NODE_NUM * DIM * 4);
    float* F1     = (float*)alloc((size_t)NODE_NUM * DIM * 4);
    // total ws use ~65.3 MB

    // ---- CSR build ----
    hipMemsetAsync(deg, 0, (size_t)NODE_NUM * 4, stream);
    int eb = (NNZ_N + 255) / 256;            // 6250
    int nb = (NODE_NUM + 1023) / 1024;       // 98
    k_count<<<eb, 256, 0, stream>>>(row, deg, NNZ_N);
    k_scan_blk<<<nb, 1024, 0, stream>>>(deg, ptr, bsums, NODE_NUM);
    k_scan_tops<<<1, 128, 0, stream>>>(bsums, nb);
    k_scan_add<<<nb, 1024, 0, stream>>>(ptr, bsums, NODE_NUM);
    k_copy_i32<<<nb, 1024, 0, stream>>>(ptr, cursor, NODE_NUM);
    k_scatter<<<eb, 256, 0, stream>>>(row, col, vals, cursor, ccol, cval, NNZ_N);

    // ---- layer 0 columns (raw embeddings, exact copy) ----
    k_gather<<<2048, 256, 0, stream>>>(emb, out, uidx, iidx, 0);

    // ---- 3 propagation layers (fused spmm+dense), ping-pong F0/F1 ----
    k_layer<<<2048, 256, 0, stream>>>(ptr, deg, ccol, cval, emb, W1, W2, F0);
    k_gather<<<2048, 256, 0, stream>>>(F0, out, uidx, iidx, 1);
    k_layer<<<2048, 256, 0, stream>>>(ptr, deg, ccol, cval, F0, W1 + 4096, W2 + 4096, F1);
    k_gather<<<2048, 256, 0, stream>>>(F1, out, uidx, iidx, 2);
    k_layer<<<2048, 256, 0, stream>>>(ptr, deg, ccol, cval, F1, W1 + 8192, W2 + 8192, F0);
    k_gather<<<2048, 256, 0, stream>>>(F0, out, uidx, iidx, 3);
}

// Round 5
// 671.422 us; speedup vs baseline: 1.7433x; 1.7433x over previous
//
#include <hip/hip_runtime.h>
#include <hip/hip_bf16.h>

#define USER_NUM 60000
#define ITEM_NUM 40000
#define NODE_NUM 100000
#define DIM 64
#define NNZ_N 1600000
#define BATCH 4096
#define NEG 0.2f
#define NCHUNK (NODE_NUM / 4)   // 25000 chunks of 4 rows

// ---------------- CSR build ----------------
__global__ void k_count(const int* __restrict__ row, int* __restrict__ deg, int n) {
    int i = blockIdx.x * 256 + threadIdx.x;
    if (i < n) atomicAdd(&deg[row[i]], 1);
}

// phase 1: per-block inclusive scan (1024 elems/block), write exclusive
__global__ void k_scan_blk(const int* __restrict__ deg, int* __restrict__ ptr,
                           int* __restrict__ bsums, int n) {
    __shared__ int sh[1024];
    int t = threadIdx.x;
    int i = blockIdx.x * 1024 + t;
    int v = (i < n) ? deg[i] : 0;
    sh[t] = v;
    __syncthreads();
    for (int d = 1; d < 1024; d <<= 1) {
        int x = (t >= d) ? sh[t - d] : 0;
        __syncthreads();
        sh[t] += x;
        __syncthreads();
    }
    if (i < n) ptr[i] = sh[t] - v;
    if (t == 1023) bsums[blockIdx.x] = sh[1023];
}

__global__ void k_scan_tops(int* bsums, int nb) {
    __shared__ int sh[128];
    int t = threadIdx.x;
    int v = (t < nb) ? bsums[t] : 0;
    sh[t] = v;
    __syncthreads();
    for (int d = 1; d < 128; d <<= 1) {
        int x = (t >= d) ? sh[t - d] : 0;
        __syncthreads();
        sh[t] += x;
        __syncthreads();
    }
    if (t < nb) bsums[t] = sh[t] - v;
}

__global__ void k_scan_add(int* __restrict__ ptr, const int* __restrict__ bsums, int n) {
    int i = blockIdx.x * 1024 + threadIdx.x;
    if (i < n) ptr[i] += bsums[blockIdx.x];
}

__global__ void k_copy_i32(const int* __restrict__ src, int* __restrict__ dst, int n) {
    int i = blockIdx.x * 1024 + threadIdx.x;
    if (i < n) dst[i] = src[i];
}

// scatter edges into CSR slots; cursor bumped, ptr keeps row starts
__global__ void k_scatter(const int* __restrict__ row, const int* __restrict__ col,
                          const float* __restrict__ vals, int* __restrict__ cursor,
                          int* __restrict__ ccol, float* __restrict__ cval, int n) {
    int i = blockIdx.x * 256 + threadIdx.x;
    if (i < n) {
        int r = row[i];
        int pos = atomicAdd(&cursor[r], 1);
        ccol[pos] = col[i];
        cval[pos] = vals[i];
    }
}

// ---------------- SpMM: one wave per row, lane = dim, zero LDS ----------------
// edge indices/vals preloaded 64-at-a-time via one coalesced load + shfl broadcast;
// gather loop unrolled 4x for MLP.
__launch_bounds__(256)
__global__ void k_spmm(const int* __restrict__ ptrS, const int* __restrict__ deg,
                       const int* __restrict__ ccol, const float* __restrict__ cval,
                       const float* __restrict__ Ein, float* __restrict__ S) {
    int w = (blockIdx.x * 256 + threadIdx.x) >> 6;   // global wave id = row
    int lane = threadIdx.x & 63;
    if (w >= NODE_NUM) return;
    int s0 = ptrS[w];
    int e0 = s0 + deg[w];
    float acc = 0.f;
    for (int base = s0; base < e0; base += 64) {
        int n = e0 - base;
        if (n > 64) n = 64;
        int c = 0;
        float v = 0.f;
        if (lane < n) {
            c = ccol[base + lane];
            v = cval[base + lane];
        }
        int i = 0;
        for (; i + 4 <= n; i += 4) {
            int c0 = __shfl(c, i), c1 = __shfl(c, i + 1);
            int c2 = __shfl(c, i + 2), c3 = __shfl(c, i + 3);
            float v0 = __shfl(v, i), v1 = __shfl(v, i + 1);
            float v2 = __shfl(v, i + 2), v3 = __shfl(v, i + 3);
            float g0 = Ein[(size_t)c0 * 64 + lane];
            float g1 = Ein[(size_t)c1 * 64 + lane];
            float g2 = Ein[(size_t)c2 * 64 + lane];
            float g3 = Ein[(size_t)c3 * 64 + lane];
            acc = fmaf(v0, g0, acc);
            acc = fmaf(v1, g1, acc);
            acc = fmaf(v2, g2, acc);
            acc = fmaf(v3, g3, acc);
        }
        for (; i < n; ++i) {
            int cc = __shfl(c, i);
            float vv = __shfl(v, i);
            acc = fmaf(vv, Ein[(size_t)cc * 64 + lane], acc);
        }
    }
    S[(size_t)w * 64 + lane] = acc;
}

// ---------------- dense: bi-interaction + 2 GEMMs + leaky-relu ----------------
__launch_bounds__(256)
__global__ void k_dense(const float* __restrict__ Eprev, const float* __restrict__ S,
                        const float* __restrict__ W1l, const float* __restrict__ W2l,
                        float* __restrict__ Eout) {
    __shared__ float w1[4096], w2[4096], su[256], bi[256];
    int t = threadIdx.x;
    for (int i = t; i < 4096; i += 256) { w1[i] = W1l[i]; w2[i] = W2l[i]; }
    __syncthreads();
    int rowl = t >> 6, d = t & 63;
    for (int ch = blockIdx.x; ch < NCHUNK; ch += gridDim.x) {
        int r = ch * 4 + rowl;
        float e = Eprev[(size_t)r * 64 + d];
        float s = S[(size_t)r * 64 + d];
        su[t] = e + s;
        bi[t] = e * s;
        __syncthreads();
        float a1 = 0.f, a2 = 0.f;
#pragma unroll
        for (int k = 0; k < 64; k++) {
            a1 = fmaf(su[rowl * 64 + k], w1[k * 64 + d], a1);
            a2 = fmaf(bi[rowl * 64 + k], w2[k * 64 + d], a2);
        }
        float x = a1 + a2;
        Eout[(size_t)r * 64 + d] = x > 0.f ? x : NEG * x;
        __syncthreads();
    }
}

// ---------------- gather one 64-col layer block into fp32 output ----------------
__global__ void k_gather(const float* __restrict__ E, float* __restrict__ out,
                         const int* __restrict__ uidx, const int* __restrict__ iidx,
                         int layer) {
    int g = blockIdx.x * 256 + threadIdx.x;
    int b = g >> 6, d = g & 63;
    if (b >= 2 * BATCH) return;
    int node;
    size_t obase;
    if (b < BATCH) {
        node = uidx[b];
        obase = (size_t)b * 256;
    } else {
        int bb = b - BATCH;
        node = USER_NUM + iidx[bb];
        obase = (size_t)BATCH * 256 + (size_t)bb * 256;
    }
    out[obase + layer * 64 + d] = E[(size_t)node * 64 + d];
}

extern "C" void kernel_launch(void* const* d_in, const int* in_sizes, int n_in,
                              void* d_out, int out_size, void* d_ws, size_t ws_size,
                              hipStream_t stream) {
    const float* emb  = (const float*)d_in[0];
    const float* W1   = (const float*)d_in[1];
    const float* W2   = (const float*)d_in[2];
    const float* vals = (const float*)d_in[3];
    const int*   row  = (const int*)d_in[4];
    const int*   col  = (const int*)d_in[5];
    const int*   uidx = (const int*)d_in[6];
    const int*   iidx = (const int*)d_in[7];
    float* out = (float*)d_out;

    char* p = (char*)d_ws;
    auto alloc = [&](size_t bytes) -> void* {
        void* q = (void*)p;
        p += (bytes + 255) & ~(size_t)255;
        return q;
    };
    int*   deg    = (int*)alloc((size_t)NODE_NUM * 4);
    int*   ptr    = (int*)alloc((size_t)NODE_NUM * 4);
    int*   cursor = (int*)alloc((size_t)NODE_NUM * 4);
    int*   bsums  = (int*)alloc(128 * 4);
    int*   ccol   = (int*)alloc((size_t)NNZ_N * 4);
    float* cval   = (float*)alloc((size_t)NNZ_N * 4);
    float* Sb     = (float*)alloc((size_t)NODE_NUM * DIM * 4);
    float* F0     = (float*)alloc((size_t)NODE_NUM * DIM * 4);
    float* F1     = (float*)alloc((size_t)NODE_NUM * DIM * 4);
    // total ws use ~91 MB

    // ---- CSR build ----
    hipMemsetAsync(deg, 0, (size_t)NODE_NUM * 4, stream);
    int eb = (NNZ_N + 255) / 256;            // 6250
    int nb = (NODE_NUM + 1023) / 1024;       // 98
    k_count<<<eb, 256, 0, stream>>>(row, deg, NNZ_N);
    k_scan_blk<<<nb, 1024, 0, stream>>>(deg, ptr, bsums, NODE_NUM);
    k_scan_tops<<<1, 128, 0, stream>>>(bsums, nb);
    k_scan_add<<<nb, 1024, 0, stream>>>(ptr, bsums, NODE_NUM);
    k_copy_i32<<<nb, 1024, 0, stream>>>(ptr, cursor, NODE_NUM);
    k_scatter<<<eb, 256, 0, stream>>>(row, col, vals, cursor, ccol, cval, NNZ_N);

    // ---- layer 0 columns (raw embeddings, exact copy) ----
    k_gather<<<2048, 256, 0, stream>>>(emb, out, uidx, iidx, 0);

    // ---- 3 propagation layers: spmm -> dense, ping-pong F0/F1 ----
    const int spmm_grid = NCHUNK;  // 25000 blocks, 4 rows (waves) each
    k_spmm<<<spmm_grid, 256, 0, stream>>>(ptr, deg, ccol, cval, emb, Sb);
    k_dense<<<2048, 256, 0, stream>>>(emb, Sb, W1, W2, F0);
    k_gather<<<2048, 256, 0, stream>>>(F0, out, uidx, iidx, 1);

    k_spmm<<<spmm_grid, 256, 0, stream>>>(ptr, deg, ccol, cval, F0, Sb);
    k_dense<<<2048, 256, 0, stream>>>(F0, Sb, W1 + 4096, W2 + 4096, F1);
    k_gather<<<2048, 256, 0, stream>>>(F1, out, uidx, iidx, 2);

    k_spmm<<<spmm_grid, 256, 0, stream>>>(ptr, deg, ccol, cval, F1, Sb);
    k_dense<<<2048, 256, 0, stream>>>(F1, Sb, W1 + 8192, W2 + 8192, F0);
    k_gather<<<2048, 256, 0, stream>>>(F0, out, uidx, iidx, 3);
}